// Round 1
// baseline (341.464 us; speedup 1.0000x reference)
//
#include <hip/hip_runtime.h>
#include <math.h>

#define BB 8
#define CC 64
#define HH 256
#define WW 256
#define HWp (HH * WW)      /* 65536 */
#define BHW (BB * HWp)     /* 524288 */
#define NK 9

// ---------------------------------------------------------------------------
// K1: channel mean+max over C=64.  One thread per 4 consecutive w positions.
// ---------------------------------------------------------------------------
__global__ __launch_bounds__(256) void reduce_c_kernel(
    const float* __restrict__ x, float* __restrict__ favg, float* __restrict__ fmax) {
    int t = blockIdx.x * 256 + threadIdx.x;          // 0 .. BHW/4-1
    int b = t / (HWp / 4);
    int p = t - b * (HWp / 4);
    const float4* xp = reinterpret_cast<const float4*>(x) + (size_t)b * CC * (HWp / 4) + p;
    float4 s = make_float4(0.f, 0.f, 0.f, 0.f);
    float4 m = make_float4(-INFINITY, -INFINITY, -INFINITY, -INFINITY);
#pragma unroll 16
    for (int c = 0; c < CC; ++c) {
        float4 v = xp[(size_t)c * (HWp / 4)];
        s.x += v.x; s.y += v.y; s.z += v.z; s.w += v.w;
        m.x = fmaxf(m.x, v.x); m.y = fmaxf(m.y, v.y);
        m.z = fmaxf(m.z, v.z); m.w = fmaxf(m.w, v.w);
    }
    const float inv = 1.0f / CC;
    reinterpret_cast<float4*>(favg)[t] = make_float4(s.x * inv, s.y * inv, s.z * inv, s.w * inv);
    reinterpret_cast<float4*>(fmax)[t] = m;
}

// ---------------------------------------------------------------------------
// K2: deformable 3x3 conv on the 2-channel feat map + global sum/sumsq reduce.
// One thread per output pixel (b,h,w).
// ---------------------------------------------------------------------------
__device__ __forceinline__ float2 bisample(const float* __restrict__ fa,
                                           const float* __restrict__ fm,
                                           int iy, int ix) {
    bool v = ((unsigned)iy < (unsigned)HH) && ((unsigned)ix < (unsigned)WW);
    int cy = iy < 0 ? 0 : (iy > HH - 1 ? HH - 1 : iy);
    int cx = ix < 0 ? 0 : (ix > WW - 1 ? WW - 1 : ix);
    int idx = cy * WW + cx;
    float a = v ? fa[idx] : 0.f;
    float m = v ? fm[idx] : 0.f;
    return make_float2(a, m);
}

__global__ __launch_bounds__(256) void dconv_kernel(
    const float* __restrict__ off, const float* __restrict__ wgt,
    const float* __restrict__ favg, const float* __restrict__ fmax,
    float* __restrict__ outmap, float* __restrict__ accum) {
    int t = blockIdx.x * 256 + threadIdx.x;          // 0 .. BHW-1
    int b = t >> 16;
    int p = t & (HWp - 1);
    int h = p >> 8;
    int w = p & (WW - 1);

    const float* ob = off + (size_t)b * (2 * NK) * HWp + p;
    const float* fa = favg + b * HWp;
    const float* fm = fmax + b * HWp;

    float wk[2 * NK];
#pragma unroll
    for (int i = 0; i < 2 * NK; ++i) wk[i] = wgt[i];   // uniform -> s_load

    float acc = 0.f;
#pragma unroll
    for (int k = 0; k < NK; ++k) {
        float dy = ob[(size_t)(2 * k) * HWp];
        float dx = ob[(size_t)(2 * k + 1) * HWp];
        float py = dy + (float)(h - 1 + k / 3);
        float px = dx + (float)(w - 1 + k % 3);
        float y0 = floorf(py), x0 = floorf(px);
        float wy = py - y0, wx = px - x0;
        int iy0 = (int)y0, ix0 = (int)x0;
        float w00 = (1.f - wy) * (1.f - wx);
        float w01 = (1.f - wy) * wx;
        float w10 = wy * (1.f - wx);
        float w11 = wy * wx;
        float2 c00 = bisample(fa, fm, iy0, ix0);
        float2 c01 = bisample(fa, fm, iy0, ix0 + 1);
        float2 c10 = bisample(fa, fm, iy0 + 1, ix0);
        float2 c11 = bisample(fa, fm, iy0 + 1, ix0 + 1);
        float s0 = w00 * c00.x + w01 * c01.x + w10 * c10.x + w11 * c11.x;
        float s1 = w00 * c00.y + w01 * c01.y + w10 * c10.y + w11 * c11.y;
        acc += wk[k] * s0 + wk[NK + k] * s1;
    }
    outmap[t] = acc;

    // block reduction of sum and sumsq, then one atomic pair per block
    float s1r = acc, s2r = acc * acc;
#pragma unroll
    for (int o = 32; o > 0; o >>= 1) {
        s1r += __shfl_down(s1r, o, 64);
        s2r += __shfl_down(s2r, o, 64);
    }
    __shared__ float ls1[4], ls2[4];
    int lane = threadIdx.x & 63, wid = threadIdx.x >> 6;
    if (lane == 0) { ls1[wid] = s1r; ls2[wid] = s2r; }
    __syncthreads();
    if (threadIdx.x == 0) {
        float t1 = ls1[0] + ls1[1] + ls1[2] + ls1[3];
        float t2 = ls2[0] + ls2[1] + ls2[2] + ls2[3];
        atomicAdd(&accum[0], t1);
        atomicAdd(&accum[1], t2);
    }
}

// ---------------------------------------------------------------------------
// K3a: per-pixel sigmoid of the normalized conv output (tiny, 2 MB map).
// ---------------------------------------------------------------------------
__global__ __launch_bounds__(256) void sig_kernel(
    const float* __restrict__ outmap, const float* __restrict__ accum,
    const float* __restrict__ gamma, const float* __restrict__ beta,
    float* __restrict__ sigmap) {
    int t = blockIdx.x * 256 + threadIdx.x;          // 0 .. BHW/4-1
    float mu = accum[0] * (1.0f / BHW);
    float var = accum[1] * (1.0f / BHW) - mu * mu;
    float rs = rsqrtf(var + 1e-5f);
    float g = gamma[0], be = beta[0];
    float4 o = reinterpret_cast<const float4*>(outmap)[t];
    float4 r;
    r.x = 1.f / (1.f + expf(-(g * (o.x - mu) * rs + be)));
    r.y = 1.f / (1.f + expf(-(g * (o.y - mu) * rs + be)));
    r.z = 1.f / (1.f + expf(-(g * (o.z - mu) * rs + be)));
    r.w = 1.f / (1.f + expf(-(g * (o.w - mu) * rs + be)));
    reinterpret_cast<float4*>(sigmap)[t] = r;
}

// ---------------------------------------------------------------------------
// K3b: out = x * sigmap (broadcast over C).  Pure bandwidth.
// ---------------------------------------------------------------------------
__global__ __launch_bounds__(256) void final_kernel(
    const float* __restrict__ x, const float* __restrict__ sigmap,
    float* __restrict__ out) {
    size_t t = (size_t)blockIdx.x * 256 + threadIdx.x;   // 0 .. B*C*HW/4-1
    const int per_b = CC * (HWp / 4);
    int b = (int)(t / per_b);
    int rem = (int)(t - (size_t)b * per_b);
    int p4 = rem & (HWp / 4 - 1);
    float4 xv = reinterpret_cast<const float4*>(x)[t];
    float4 sv = reinterpret_cast<const float4*>(sigmap)[b * (HWp / 4) + p4];
    reinterpret_cast<float4*>(out)[t] =
        make_float4(xv.x * sv.x, xv.y * sv.y, xv.z * sv.z, xv.w * sv.w);
}

// ---------------------------------------------------------------------------
extern "C" void kernel_launch(void* const* d_in, const int* in_sizes, int n_in,
                              void* d_out, int out_size, void* d_ws, size_t ws_size,
                              hipStream_t stream) {
    const float* x      = (const float*)d_in[0];
    const float* offset = (const float*)d_in[1];
    const float* weight = (const float*)d_in[2];
    const float* gamma  = (const float*)d_in[3];
    const float* beta   = (const float*)d_in[4];
    float* out = (float*)d_out;

    float* ws     = (float*)d_ws;
    float* favg   = ws;              // BHW floats; reused as sigmap after K2
    float* fmax   = ws + BHW;        // BHW floats
    float* outmap = ws + 2 * BHW;    // BHW floats
    float* accum  = ws + 3 * BHW;    // 2 floats
    float* sigmap = favg;            // alias: favg dead after K2

    hipMemsetAsync(accum, 0, 2 * sizeof(float), stream);

    reduce_c_kernel<<<(BHW / 4) / 256, 256, 0, stream>>>(x, favg, fmax);
    dconv_kernel<<<BHW / 256, 256, 0, stream>>>(offset, weight, favg, fmax, outmap, accum);
    sig_kernel<<<(BHW / 4) / 256, 256, 0, stream>>>(outmap, accum, gamma, beta, sigmap);
    final_kernel<<<((size_t)BB * CC * HWp / 4) / 256, 256, 0, stream>>>(x, sigmap, out);
}

// Round 3
// 333.962 us; speedup vs baseline: 1.0225x; 1.0225x over previous
//
#include <hip/hip_runtime.h>
#include <math.h>

#define BB 8
#define CC 64
#define HH 256
#define WW 256
#define HWp (HH * WW)      /* 65536 */
#define BHW (BB * HWp)     /* 524288 */
#define NK 9

typedef float f32x4 __attribute__((ext_vector_type(4)));

// ---------------------------------------------------------------------------
// K1: channel mean+max over C=64. One thread per 4 consecutive w positions.
// Writes interleaved (avg,max) float2 per pixel. Also zeroes accum.
// ---------------------------------------------------------------------------
__global__ __launch_bounds__(256) void reduce_c_kernel(
    const float* __restrict__ x, float* __restrict__ feat, float* __restrict__ accum) {
    int t = blockIdx.x * 256 + threadIdx.x;          // 0 .. BHW/4-1
    if (blockIdx.x == 0 && threadIdx.x < 2) accum[threadIdx.x] = 0.f;
    int b = t / (HWp / 4);
    int p = t - b * (HWp / 4);
    const f32x4* xp = reinterpret_cast<const f32x4*>(x) + (size_t)b * CC * (HWp / 4) + p;
    f32x4 s = {0.f, 0.f, 0.f, 0.f};
    f32x4 m = {-INFINITY, -INFINITY, -INFINITY, -INFINITY};
#pragma unroll 16
    for (int c = 0; c < CC; ++c) {
        f32x4 v = xp[(size_t)c * (HWp / 4)];
        s += v;
        m.x = fmaxf(m.x, v.x); m.y = fmaxf(m.y, v.y);
        m.z = fmaxf(m.z, v.z); m.w = fmaxf(m.w, v.w);
    }
    const float inv = 1.0f / CC;
    // interleaved (avg,max): pixel q -> feat[2q], feat[2q+1]
    f32x4 o0 = {s.x * inv, m.x, s.y * inv, m.y};
    f32x4 o1 = {s.z * inv, m.z, s.w * inv, m.w};
    f32x4* fp = reinterpret_cast<f32x4*>(feat) + 2 * (size_t)t;
    __builtin_nontemporal_store(o0, fp);
    __builtin_nontemporal_store(o1, fp + 1);
}

// ---------------------------------------------------------------------------
// K2: deformable 3x3 conv on the 2-channel feat map + global sum/sumsq reduce.
// One thread per output pixel (b,h,w). feat is interleaved float2 (avg,max).
// ---------------------------------------------------------------------------
__device__ __forceinline__ float2 bisample(const float2* __restrict__ f, int iy, int ix) {
    bool v = ((unsigned)iy < (unsigned)HH) && ((unsigned)ix < (unsigned)WW);
    int cy = iy < 0 ? 0 : (iy > HH - 1 ? HH - 1 : iy);
    int cx = ix < 0 ? 0 : (ix > WW - 1 ? WW - 1 : ix);
    float2 r = f[cy * WW + cx];
    return v ? r : make_float2(0.f, 0.f);
}

__global__ __launch_bounds__(256) void dconv_kernel(
    const float* __restrict__ off, const float* __restrict__ wgt,
    const float* __restrict__ feat, float* __restrict__ outmap,
    float* __restrict__ accum) {
    int t = blockIdx.x * 256 + threadIdx.x;          // 0 .. BHW-1
    int b = t >> 16;
    int p = t & (HWp - 1);
    int h = p >> 8;
    int w = p & (WW - 1);

    const float* ob = off + (size_t)b * (2 * NK) * HWp + p;
    const float2* f = reinterpret_cast<const float2*>(feat) + (size_t)b * HWp;

    float wk[2 * NK];
#pragma unroll
    for (int i = 0; i < 2 * NK; ++i) wk[i] = wgt[i];   // uniform -> s_load

    float acc = 0.f;
#pragma unroll
    for (int k = 0; k < NK; ++k) {
        float dy = ob[(size_t)(2 * k) * HWp];
        float dx = ob[(size_t)(2 * k + 1) * HWp];
        float py = dy + (float)(h - 1 + k / 3);
        float px = dx + (float)(w - 1 + k % 3);
        float y0 = floorf(py), x0 = floorf(px);
        float wy = py - y0, wx = px - x0;
        int iy0 = (int)y0, ix0 = (int)x0;
        float w00 = (1.f - wy) * (1.f - wx);
        float w01 = (1.f - wy) * wx;
        float w10 = wy * (1.f - wx);
        float w11 = wy * wx;
        float2 c00 = bisample(f, iy0, ix0);
        float2 c01 = bisample(f, iy0, ix0 + 1);
        float2 c10 = bisample(f, iy0 + 1, ix0);
        float2 c11 = bisample(f, iy0 + 1, ix0 + 1);
        float s0 = w00 * c00.x + w01 * c01.x + w10 * c10.x + w11 * c11.x;
        float s1 = w00 * c00.y + w01 * c01.y + w10 * c10.y + w11 * c11.y;
        acc += wk[k] * s0 + wk[NK + k] * s1;
    }
    outmap[t] = acc;

    // block reduction of sum and sumsq, then one atomic pair per block
    float s1r = acc, s2r = acc * acc;
#pragma unroll
    for (int o = 32; o > 0; o >>= 1) {
        s1r += __shfl_down(s1r, o, 64);
        s2r += __shfl_down(s2r, o, 64);
    }
    __shared__ float ls1[4], ls2[4];
    int lane = threadIdx.x & 63, wid = threadIdx.x >> 6;
    if (lane == 0) { ls1[wid] = s1r; ls2[wid] = s2r; }
    __syncthreads();
    if (threadIdx.x == 0) {
        float t1 = ls1[0] + ls1[1] + ls1[2] + ls1[3];
        float t2 = ls2[0] + ls2[1] + ls2[2] + ls2[3];
        atomicAdd(&accum[0], t1);
        atomicAdd(&accum[1], t2);
    }
}

// ---------------------------------------------------------------------------
// K3a: per-pixel sigmoid of the normalized conv output (tiny, 2 MB map).
// ---------------------------------------------------------------------------
__global__ __launch_bounds__(256) void sig_kernel(
    const float* __restrict__ outmap, const float* __restrict__ accum,
    const float* __restrict__ gamma, const float* __restrict__ beta,
    float* __restrict__ sigmap) {
    int t = blockIdx.x * 256 + threadIdx.x;          // 0 .. BHW/4-1
    float mu = accum[0] * (1.0f / BHW);
    float var = accum[1] * (1.0f / BHW) - mu * mu;
    float rs = rsqrtf(var + 1e-5f);
    float g = gamma[0], be = beta[0];
    f32x4 o = reinterpret_cast<const f32x4*>(outmap)[t];
    f32x4 r;
    r.x = 1.f / (1.f + expf(-(g * (o.x - mu) * rs + be)));
    r.y = 1.f / (1.f + expf(-(g * (o.y - mu) * rs + be)));
    r.z = 1.f / (1.f + expf(-(g * (o.z - mu) * rs + be)));
    r.w = 1.f / (1.f + expf(-(g * (o.w - mu) * rs + be)));
    reinterpret_cast<f32x4*>(sigmap)[t] = r;
}

// ---------------------------------------------------------------------------
// K3b: out = x * sigmap (broadcast over C). Pure bandwidth; nt stores so the
// out stream doesn't evict x from L3 (x should be L3-resident from K1).
// ---------------------------------------------------------------------------
__global__ __launch_bounds__(256) void final_kernel(
    const float* __restrict__ x, const float* __restrict__ sigmap,
    float* __restrict__ out) {
    size_t t = (size_t)blockIdx.x * 256 + threadIdx.x;   // 0 .. B*C*HW/4-1
    const int per_b = CC * (HWp / 4);
    int b = (int)(t / per_b);
    int rem = (int)(t - (size_t)b * per_b);
    int p4 = rem & (HWp / 4 - 1);
    f32x4 xv = reinterpret_cast<const f32x4*>(x)[t];
    f32x4 sv = reinterpret_cast<const f32x4*>(sigmap)[b * (HWp / 4) + p4];
    f32x4 r = xv * sv;
    __builtin_nontemporal_store(r, reinterpret_cast<f32x4*>(out) + t);
}

// ---------------------------------------------------------------------------
extern "C" void kernel_launch(void* const* d_in, const int* in_sizes, int n_in,
                              void* d_out, int out_size, void* d_ws, size_t ws_size,
                              hipStream_t stream) {
    const float* x      = (const float*)d_in[0];
    const float* offset = (const float*)d_in[1];
    const float* weight = (const float*)d_in[2];
    const float* gamma  = (const float*)d_in[3];
    const float* beta   = (const float*)d_in[4];
    float* out = (float*)d_out;

    float* ws     = (float*)d_ws;
    float* feat   = ws;              // 2*BHW floats, interleaved (avg,max)
    float* outmap = ws + 2 * BHW;    // BHW floats
    float* accum  = ws + 3 * BHW;    // 2 floats
    float* sigmap = feat;            // alias: feat dead after K2

    reduce_c_kernel<<<(BHW / 4) / 256, 256, 0, stream>>>(x, feat, accum);
    dconv_kernel<<<BHW / 256, 256, 0, stream>>>(offset, weight, feat, outmap, accum);
    sig_kernel<<<(BHW / 4) / 256, 256, 0, stream>>>(outmap, accum, gamma, beta, sigmap);
    final_kernel<<<((size_t)BB * CC * HWp / 4) / 256, 256, 0, stream>>>(x, sigmap, out);
}